// Round 2
// baseline (846.728 us; speedup 1.0000x reference)
//
#include <hip/hip_runtime.h>

#define IN_DIM 128
#define OUT_DIM 128
#define NHEAD 8
#define HD 16
#define BB 8
#define NN 1024
#define NEGV (-1e30f)

typedef unsigned long long u64;

// ---------------- Kernel P: pack adj_mask into 64-bit masks ----------------
// bits[w] covers adj flat indices [w*64, w*64+63]; layout matches (b, i, k)
// with k = j>>6 (16 words per row).
__global__ __launch_bounds__(256) void k_pack(const int* __restrict__ adj,
                                              u64* __restrict__ bits) {
    int lane = threadIdx.x & 63;
    int wid = blockIdx.x * 4 + (threadIdx.x >> 6);
    for (int w = wid; w < BB * NN * 16; w += 2048 * 4) {
        int v = adj[(size_t)w * 64 + lane];
        u64 m = __ballot(v != 0);
        if (lane == 0) bits[w] = m;
    }
}

// ---------------- Kernel A: Wh[b,h,n,d] = sum_i h[b,n,i] * W[h,i,d] --------
// grid = B * 32 (32-row tiles), block = 256.
// LDS: h tile [32][132] + W transposed [(h*16+d)][132] (rows over i).
__global__ __launch_bounds__(256) void k_wh(const float* __restrict__ hin,
                                            const float* __restrict__ W,
                                            float* __restrict__ wh) {
    extern __shared__ float smem[];
    float* h_s  = smem;             // 32 * 132
    float* wt_s = smem + 32 * 132;  // 128 * 132
    int t = threadIdx.x;
    int blk = blockIdx.x;
    int b = blk >> 5;
    int ntile = blk & 31;
    const float* hrow = hin + ((size_t)b * NN + ntile * 32) * IN_DIM;

    // stage h tile: 1024 float4
#pragma unroll
    for (int it = 0; it < 4; ++it) {
        int g = t + 256 * it;
        int row = g >> 5, c4 = g & 31;
        float4 v = ((const float4*)hrow)[g];
        *(float4*)&h_s[row * 132 + c4 * 4] = v;
    }
    // stage W transposed: ALL 4096 float4 of W (8*128*16 floats)
    for (int g = t; g < (NHEAD * IN_DIM * HD) / 4; g += 256) {
        int hh = g >> 9;             // head (512 f4 per head)
        int rem = g & 511;
        int i = rem >> 2, d4 = rem & 3;
        float4 v = ((const float4*)W)[g];
        wt_s[(hh * 16 + d4 * 4 + 0) * 132 + i] = v.x;
        wt_s[(hh * 16 + d4 * 4 + 1) * 132 + i] = v.y;
        wt_s[(hh * 16 + d4 * 4 + 2) * 132 + i] = v.z;
        wt_s[(hh * 16 + d4 * 4 + 3) * 132 + i] = v.w;
    }
    __syncthreads();

    int hq = (t & 31) >> 2;  // head
    int d4 = t & 3;          // d-group
    int ngrp = t >> 5;       // n-group (4 rows)
    float acc[4][4];
#pragma unroll
    for (int q = 0; q < 4; ++q)
#pragma unroll
        for (int dd = 0; dd < 4; ++dd) acc[q][dd] = 0.f;

    for (int i4 = 0; i4 < 32; ++i4) {
        float4 wr[4], hv[4];
#pragma unroll
        for (int dd = 0; dd < 4; ++dd)
            wr[dd] = *(const float4*)&wt_s[(hq * 16 + d4 * 4 + dd) * 132 + i4 * 4];
#pragma unroll
        for (int q = 0; q < 4; ++q)
            hv[q] = *(const float4*)&h_s[(ngrp * 4 + q) * 132 + i4 * 4];
#pragma unroll
        for (int q = 0; q < 4; ++q)
#pragma unroll
            for (int dd = 0; dd < 4; ++dd)
                acc[q][dd] += hv[q].x * wr[dd].x + hv[q].y * wr[dd].y +
                              hv[q].z * wr[dd].z + hv[q].w * wr[dd].w;
    }
#pragma unroll
    for (int q = 0; q < 4; ++q) {
        int row = ntile * 32 + ngrp * 4 + q;
        float4 o = make_float4(acc[q][0], acc[q][1], acc[q][2], acc[q][3]);
        *(float4*)&wh[(((size_t)b * NHEAD + hq) * NN + row) * HD + d4 * 4] = o;
    }
}

// ---------------- Kernel B: attention per (b,h) -----------------------------
// grid = B*H*16 (64-row chunks), block = 512 (8 waves).
// LDS: Wh[b,h] padded [1024][18] + s_j[1024] + a[h][32].
__global__ __launch_bounds__(512, 4) void k_attn(const float* __restrict__ wh,
                                                 const u64* __restrict__ bits,
                                                 const float* __restrict__ a,
                                                 float* __restrict__ hh) {
    extern __shared__ float smem[];
    float* wh_s = smem;              // 1024*18
    float* sj_s = smem + 1024 * 18;  // 1024
    float* a_s  = sj_s + 1024;       // 32
    int t = threadIdx.x;
    int blk = blockIdx.x;
    int chunk = blk & 15;
    int bh = blk >> 4;
    int hq = bh & 7;
    int b = bh >> 3;
    const float* whg = wh + (size_t)bh * (NN * HD);

    for (int g = t; g < NN * HD / 2; g += 512) {
        int row = g >> 3, c2 = (g & 7) * 2;
        *(float2*)&wh_s[row * 18 + c2] = *(const float2*)&whg[row * 16 + c2];
    }
    if (t < 32) a_s[t] = a[hq * 32 + t];
    __syncthreads();

    for (int j = t; j < NN; j += 512) {
        float s = 0.f;
#pragma unroll
        for (int d = 0; d < 16; ++d) s += wh_s[j * 18 + d] * a_s[16 + d];
        sj_s[j] = s;
    }
    __syncthreads();

    int wave = t >> 6, lane = t & 63;
    u64 lm = 1ull << lane;
    const u64* bitb = bits + (size_t)b * NN * 16;
    int i0b = chunk * 64 + wave * 8;

    for (int pr = 0; pr < 4; ++pr) {
        int i0 = i0b + pr * 2;
        int i1 = i0 + 1;
        float si0 = 0.f, si1 = 0.f;
#pragma unroll
        for (int d = 0; d < 16; ++d) {
            si0 += wh_s[i0 * 18 + d] * a_s[d];
            si1 += wh_s[i1 * 18 + d] * a_s[d];
        }
        float e0[16], e1[16];
        float mx0 = NEGV, mx1 = NEGV;
#pragma unroll
        for (int k = 0; k < 16; ++k) {
            int j = lane + (k << 6);
            float sj = sj_s[j];
            u64 w0 = bitb[i0 * 16 + k];   // wave-uniform -> scalar load
            u64 w1v = bitb[i1 * 16 + k];
            float v0 = si0 + sj; v0 = v0 >= 0.f ? v0 : 0.2f * v0;
            float v1 = si1 + sj; v1 = v1 >= 0.f ? v1 : 0.2f * v1;
            e0[k] = (w0 & lm) ? v0 : NEGV;
            e1[k] = (w1v & lm) ? v1 : NEGV;
            mx0 = fmaxf(mx0, e0[k]);
            mx1 = fmaxf(mx1, e1[k]);
        }
#pragma unroll
        for (int off = 32; off > 0; off >>= 1) {
            mx0 = fmaxf(mx0, __shfl_xor(mx0, off));
            mx1 = fmaxf(mx1, __shfl_xor(mx1, off));
        }
        float sum0 = 0.f, sum1 = 0.f;
#pragma unroll
        for (int k = 0; k < 16; ++k) {
            float p0 = __expf(e0[k] - mx0); e0[k] = p0; sum0 += p0;
            float p1 = __expf(e1[k] - mx1); e1[k] = p1; sum1 += p1;
        }
#pragma unroll
        for (int off = 32; off > 0; off >>= 1) {
            sum0 += __shfl_xor(sum0, off);
            sum1 += __shfl_xor(sum1, off);
        }
        float acc0[16], acc1[16];
#pragma unroll
        for (int d = 0; d < 16; ++d) { acc0[d] = 0.f; acc1[d] = 0.f; }
#pragma unroll
        for (int k = 0; k < 16; ++k) {
            const float* wr = &wh_s[(lane + (k << 6)) * 18];
            float p0 = e0[k], p1 = e1[k];
#pragma unroll
            for (int d2 = 0; d2 < 8; ++d2) {
                float2 wv = *(const float2*)&wr[d2 * 2];
                acc0[d2 * 2 + 0] += p0 * wv.x;
                acc0[d2 * 2 + 1] += p0 * wv.y;
                acc1[d2 * 2 + 0] += p1 * wv.x;
                acc1[d2 * 2 + 1] += p1 * wv.y;
            }
        }
        float r0 = (mx0 > -1e29f) ? 1.0f / sum0 : 0.0f;
        float r1 = (mx1 > -1e29f) ? 1.0f / sum1 : 0.0f;
#pragma unroll
        for (int off = 32; off > 0; off >>= 1) {
#pragma unroll
            for (int d = 0; d < 16; ++d) {
                acc0[d] += __shfl_xor(acc0[d], off);
                acc1[d] += __shfl_xor(acc1[d], off);
            }
        }
        if (lane == 0) {
            float* o0 = &hh[((size_t)b * NN + i0) * OUT_DIM + hq * HD];
            float* o1 = &hh[((size_t)b * NN + i1) * OUT_DIM + hq * HD];
#pragma unroll
            for (int d4 = 0; d4 < 4; ++d4) {
                *(float4*)&o0[d4 * 4] = make_float4(acc0[d4 * 4] * r0, acc0[d4 * 4 + 1] * r0,
                                                    acc0[d4 * 4 + 2] * r0, acc0[d4 * 4 + 3] * r0);
                *(float4*)&o1[d4 * 4] = make_float4(acc1[d4 * 4] * r1, acc1[d4 * 4 + 1] * r1,
                                                    acc1[d4 * 4 + 2] * r1, acc1[d4 * 4 + 3] * r1);
            }
        }
    }
}

// ---------------- Kernel C: LN1 + FFN + LN2, 16 rows per block --------------
__global__ __launch_bounds__(256) void k_ffn(const float* __restrict__ hhs,
                                             const float* __restrict__ hin,
                                             const float* __restrict__ g1,
                                             const float* __restrict__ bt1,
                                             const float* __restrict__ w1,
                                             const float* __restrict__ bb1,
                                             const float* __restrict__ w2,
                                             const float* __restrict__ bb2,
                                             const float* __restrict__ g2,
                                             const float* __restrict__ bt2,
                                             float* __restrict__ out) {
    __shared__ float xc[16][128];
    __shared__ float hid[16][256];
    __shared__ float2 red[16][2];
    int t = threadIdx.x;
    int R0 = blockIdx.x * 16;
    int wave = t >> 6, lane = t & 63;

    // phase 1: residual + LN1, one wave owns 4 full rows
#pragma unroll
    for (int q = 0; q < 4; ++q) {
        int r = wave * 4 + q;
        size_t row = (size_t)(R0 + r) * 128;
        float x0 = hhs[row + lane] + hin[row + lane];
        float x1 = hhs[row + 64 + lane] + hin[row + 64 + lane];
        float s = x0 + x1, s2 = x0 * x0 + x1 * x1;
#pragma unroll
        for (int off = 32; off > 0; off >>= 1) {
            s += __shfl_xor(s, off);
            s2 += __shfl_xor(s2, off);
        }
        float mu = s * (1.f / 128.f);
        float var = s2 * (1.f / 128.f) - mu * mu;
        float rs = rsqrtf(var + 1e-5f);
        xc[r][lane]      = (x0 - mu) * rs * g1[lane] + bt1[lane];
        xc[r][lane + 64] = (x1 - mu) * rs * g1[lane + 64] + bt1[lane + 64];
    }
    __syncthreads();

    // phase 2: hidden = relu(xc @ w1 + b1), thread t owns column o=t, 16 rows
    {
        int o = t;
        float acc[16];
#pragma unroll
        for (int r = 0; r < 16; ++r) acc[r] = bb1[o];
        for (int k4 = 0; k4 < 32; ++k4) {
            float wv[4];
#pragma unroll
            for (int e = 0; e < 4; ++e) wv[e] = w1[(k4 * 4 + e) * 256 + o];
#pragma unroll
            for (int r = 0; r < 16; ++r) {
                float4 xv = *(const float4*)&xc[r][k4 * 4];
                acc[r] += xv.x * wv[0] + xv.y * wv[1] + xv.z * wv[2] + xv.w * wv[3];
            }
        }
#pragma unroll
        for (int r = 0; r < 16; ++r) hid[r][o] = fmaxf(acc[r], 0.f);
    }
    __syncthreads();

    // phase 3: y = hid @ w2 + b2 ; resid = xc + y ; LN2 ; store
    int d = t & 127;
    int g = t >> 7;  // row group: rows g*8 .. g*8+7
    float acc[8];
#pragma unroll
    for (int q = 0; q < 8; ++q) acc[q] = bb2[d];
    for (int k4 = 0; k4 < 64; ++k4) {
        float wv[4];
#pragma unroll
        for (int e = 0; e < 4; ++e) wv[e] = w2[(k4 * 4 + e) * 128 + d];
#pragma unroll
        for (int q = 0; q < 8; ++q) {
            float4 hv = *(const float4*)&hid[g * 8 + q][k4 * 4];
            acc[q] += hv.x * wv[0] + hv.y * wv[1] + hv.z * wv[2] + hv.w * wv[3];
        }
    }
    float resid[8];
#pragma unroll
    for (int q = 0; q < 8; ++q) resid[q] = xc[g * 8 + q][d] + acc[q];

    int halfsel = (t >> 6) & 1;
#pragma unroll
    for (int q = 0; q < 8; ++q) {
        float s = resid[q], s2 = resid[q] * resid[q];
#pragma unroll
        for (int off = 32; off > 0; off >>= 1) {
            s += __shfl_xor(s, off);
            s2 += __shfl_xor(s2, off);
        }
        if (lane == 0) red[g * 8 + q][halfsel] = make_float2(s, s2);
    }
    __syncthreads();
#pragma unroll
    for (int q = 0; q < 8; ++q) {
        int r = g * 8 + q;
        float2 ra = red[r][0], rb = red[r][1];
        float s = ra.x + rb.x, s2 = ra.y + rb.y;
        float mu = s * (1.f / 128.f);
        float var = s2 * (1.f / 128.f) - mu * mu;
        float rs = rsqrtf(var + 1e-5f);
        out[(size_t)(R0 + r) * 128 + d] = (resid[q] - mu) * rs * g2[d] + bt2[d];
    }
}

extern "C" void kernel_launch(void* const* d_in, const int* in_sizes, int n_in,
                              void* d_out, int out_size, void* d_ws, size_t ws_size,
                              hipStream_t stream) {
    const float* hin  = (const float*)d_in[0];
    const int*   adj  = (const int*)d_in[1];
    const float* W    = (const float*)d_in[2];
    const float* a    = (const float*)d_in[3];
    const float* ln1g = (const float*)d_in[4];
    const float* ln1b = (const float*)d_in[5];
    const float* w1   = (const float*)d_in[6];
    const float* b1   = (const float*)d_in[7];
    const float* w2   = (const float*)d_in[8];
    const float* b2   = (const float*)d_in[9];
    const float* ln2g = (const float*)d_in[10];
    const float* ln2b = (const float*)d_in[11];
    float* out = (float*)d_out;

    float* wh   = (float*)d_ws;                            // 4 MB
    u64*   bits = (u64*)((char*)d_ws + (4u << 20));        // 1 MB
    float* hh   = (float*)((char*)d_ws + (5u << 20));      // 4 MB

    k_pack<<<2048, 256, 0, stream>>>(adj, bits);
    k_wh<<<BB * 32, 256, (32 * 132 + 128 * 132) * sizeof(float), stream>>>(hin, W, wh);
    k_attn<<<BB * NHEAD * 16, 512, (1024 * 18 + 1024 + 32) * sizeof(float), stream>>>(wh, bits, a, hh);
    k_ffn<<<BB * NN / 16, 256, 0, stream>>>(hh, hin, ln1g, ln1b, w1, b1, w2, b2, ln2g, ln2b, out);
}

// Round 3
// 132.594 us; speedup vs baseline: 6.3859x; 6.3859x over previous
//
#include <hip/hip_runtime.h>

#define IN_DIM 128
#define OUT_DIM 128
#define NHEAD 8
#define HD 16
#define BB 8
#define NN 1024

typedef unsigned long long u64;

// ---------------- Kernel P: pack adj_mask into 64-bit masks ----------------
__global__ __launch_bounds__(256) void k_pack(const int* __restrict__ adj,
                                              u64* __restrict__ bits) {
    int lane = threadIdx.x & 63;
    int wid = blockIdx.x * 4 + (threadIdx.x >> 6);
    for (int w = wid; w < BB * NN * 16; w += 2048 * 4) {
        int v = adj[(size_t)w * 64 + lane];
        u64 m = __ballot(v != 0);
        if (lane == 0) bits[w] = m;
    }
}

// ---------------- Kernel A: Wh[b,h,n,d] = sum_i h[b,n,i] * W[h,i,d] --------
__global__ __launch_bounds__(256) void k_wh(const float* __restrict__ hin,
                                            const float* __restrict__ W,
                                            float* __restrict__ wh) {
    extern __shared__ float smem[];
    float* h_s  = smem;             // 32 * 132
    float* wt_s = smem + 32 * 132;  // 128 * 132
    int t = threadIdx.x;
    int blk = blockIdx.x;
    int b = blk >> 5;
    int ntile = blk & 31;
    const float* hrow = hin + ((size_t)b * NN + ntile * 32) * IN_DIM;

#pragma unroll
    for (int it = 0; it < 4; ++it) {
        int g = t + 256 * it;
        int row = g >> 5, c4 = g & 31;
        float4 v = ((const float4*)hrow)[g];
        *(float4*)&h_s[row * 132 + c4 * 4] = v;
    }
    for (int g = t; g < (NHEAD * IN_DIM * HD) / 4; g += 256) {
        int hh = g >> 9;
        int rem = g & 511;
        int i = rem >> 2, d4 = rem & 3;
        float4 v = ((const float4*)W)[g];
        wt_s[(hh * 16 + d4 * 4 + 0) * 132 + i] = v.x;
        wt_s[(hh * 16 + d4 * 4 + 1) * 132 + i] = v.y;
        wt_s[(hh * 16 + d4 * 4 + 2) * 132 + i] = v.z;
        wt_s[(hh * 16 + d4 * 4 + 3) * 132 + i] = v.w;
    }
    __syncthreads();

    int hq = (t & 31) >> 2;
    int d4 = t & 3;
    int ngrp = t >> 5;
    float acc[4][4];
#pragma unroll
    for (int q = 0; q < 4; ++q)
#pragma unroll
        for (int dd = 0; dd < 4; ++dd) acc[q][dd] = 0.f;

    for (int i4 = 0; i4 < 32; ++i4) {
        float4 wr[4], hv[4];
#pragma unroll
        for (int dd = 0; dd < 4; ++dd)
            wr[dd] = *(const float4*)&wt_s[(hq * 16 + d4 * 4 + dd) * 132 + i4 * 4];
#pragma unroll
        for (int q = 0; q < 4; ++q)
            hv[q] = *(const float4*)&h_s[(ngrp * 4 + q) * 132 + i4 * 4];
#pragma unroll
        for (int q = 0; q < 4; ++q)
#pragma unroll
            for (int dd = 0; dd < 4; ++dd)
                acc[q][dd] += hv[q].x * wr[dd].x + hv[q].y * wr[dd].y +
                              hv[q].z * wr[dd].z + hv[q].w * wr[dd].w;
    }
#pragma unroll
    for (int q = 0; q < 4; ++q) {
        int row = ntile * 32 + ngrp * 4 + q;
        float4 o = make_float4(acc[q][0], acc[q][1], acc[q][2], acc[q][3]);
        *(float4*)&wh[(((size_t)b * NHEAD + hq) * NN + row) * HD + d4 * 4] = o;
    }
}

// ---------------- Kernel B: attention per (b,h) -----------------------------
// grid = B*H*16 (64-row chunks), block = 512.
// 32 threads per row-group, 4 rows per thread; single-pass softmax (no max
// subtraction — |e| <~ 10, exp never overflows f32), no e[] arrays.
// LDS: wh row stride 18 floats: [16 x Wh | s_j | pad]; banks (18c)%32 spread.
__global__ __launch_bounds__(512, 2) void k_attn(const float* __restrict__ wh,
                                                 const u64* __restrict__ bits,
                                                 const float* __restrict__ a,
                                                 float* __restrict__ hh) {
    __shared__ float wh_s[NN * 18];
    __shared__ float a_s[32];
    int t = threadIdx.x;
    int blk = blockIdx.x;
    int chunk = blk & 15;
    int bh = blk >> 4;
    int hq = bh & 7;
    int b = bh >> 3;
    const float* whg = wh + (size_t)bh * (NN * HD);

    if (t < 32) a_s[t] = a[hq * 32 + t];
    for (int g = t; g < NN * 4; g += 512) {
        int row = g >> 2, d4 = (g & 3) * 4;
        float4 v = ((const float4*)whg)[g];
        float* p = &wh_s[row * 18 + d4];
        p[0] = v.x; p[1] = v.y; p[2] = v.z; p[3] = v.w;
    }
    __syncthreads();
    // s_j into slot 16 of each row
    for (int j = t; j < NN; j += 512) {
        float s = 0.f;
#pragma unroll
        for (int d = 0; d < 16; ++d) s += wh_s[j * 18 + d] * a_s[16 + d];
        wh_s[j * 18 + 16] = s;
    }
    __syncthreads();

    int c = t & 31;              // thread-in-row-group
    int rr = t >> 5;             // 0..15
    int ibase = chunk * 64 + rr * 4;
    const u64* bitr = bits + ((size_t)b * NN + ibase) * 16;

    float si[4], l[4], acc[4][16];
#pragma unroll
    for (int r = 0; r < 4; ++r) {
        float s = 0.f;
#pragma unroll
        for (int d = 0; d < 16; ++d) s += wh_s[(ibase + r) * 18 + d] * a_s[d];
        si[r] = s;
        l[r] = 0.f;
#pragma unroll
        for (int d = 0; d < 16; ++d) acc[r][d] = 0.f;
    }

    for (int w = 0; w < 16; ++w) {
        u64 m0 = bitr[w];
        u64 m1 = bitr[16 + w];
        u64 m2 = bitr[32 + w];
        u64 m3 = bitr[48 + w];
#pragma unroll
        for (int q = 0; q < 2; ++q) {
            int bit = q * 32 + c;
            int j = w * 64 + bit;
            float sj = wh_s[j * 18 + 16];
            float2 wv[8];
#pragma unroll
            for (int d2 = 0; d2 < 8; ++d2)
                wv[d2] = *(const float2*)&wh_s[j * 18 + d2 * 2];
            float p[4];
            {
                float e0 = si[0] + sj; e0 = e0 >= 0.f ? e0 : 0.2f * e0;
                float e1 = si[1] + sj; e1 = e1 >= 0.f ? e1 : 0.2f * e1;
                float e2 = si[2] + sj; e2 = e2 >= 0.f ? e2 : 0.2f * e2;
                float e3 = si[3] + sj; e3 = e3 >= 0.f ? e3 : 0.2f * e3;
                p[0] = ((m0 >> bit) & 1) ? __expf(e0) : 0.f;
                p[1] = ((m1 >> bit) & 1) ? __expf(e1) : 0.f;
                p[2] = ((m2 >> bit) & 1) ? __expf(e2) : 0.f;
                p[3] = ((m3 >> bit) & 1) ? __expf(e3) : 0.f;
            }
#pragma unroll
            for (int r = 0; r < 4; ++r) {
                l[r] += p[r];
#pragma unroll
                for (int d2 = 0; d2 < 8; ++d2) {
                    acc[r][d2 * 2 + 0] += p[r] * wv[d2].x;
                    acc[r][d2 * 2 + 1] += p[r] * wv[d2].y;
                }
            }
        }
    }

    // merge the 32 partial states per row group (butterfly over c)
#pragma unroll
    for (int off = 16; off > 0; off >>= 1) {
#pragma unroll
        for (int r = 0; r < 4; ++r) {
            l[r] += __shfl_xor(l[r], off);
#pragma unroll
            for (int d = 0; d < 16; ++d) acc[r][d] += __shfl_xor(acc[r][d], off);
        }
    }

    if (c == 0) {
#pragma unroll
        for (int r = 0; r < 4; ++r) {
            float s = (l[r] > 0.f) ? 1.0f / l[r] : 0.f;
            float* o = &hh[((size_t)b * NN + ibase + r) * OUT_DIM + hq * HD];
#pragma unroll
            for (int d4 = 0; d4 < 4; ++d4)
                *(float4*)&o[d4 * 4] = make_float4(acc[r][d4 * 4 + 0] * s, acc[r][d4 * 4 + 1] * s,
                                                   acc[r][d4 * 4 + 2] * s, acc[r][d4 * 4 + 3] * s);
        }
    }
}

// ---------------- Kernel C: LN1 + FFN + LN2, 16 rows per block --------------
__global__ __launch_bounds__(256) void k_ffn(const float* __restrict__ hhs,
                                             const float* __restrict__ hin,
                                             const float* __restrict__ g1,
                                             const float* __restrict__ bt1,
                                             const float* __restrict__ w1,
                                             const float* __restrict__ bb1,
                                             const float* __restrict__ w2,
                                             const float* __restrict__ bb2,
                                             const float* __restrict__ g2,
                                             const float* __restrict__ bt2,
                                             float* __restrict__ out) {
    __shared__ float xc[16][128];
    __shared__ float hid[16][256];
    __shared__ float2 red[16][2];
    int t = threadIdx.x;
    int R0 = blockIdx.x * 16;
    int wave = t >> 6, lane = t & 63;

#pragma unroll
    for (int q = 0; q < 4; ++q) {
        int r = wave * 4 + q;
        size_t row = (size_t)(R0 + r) * 128;
        float x0 = hhs[row + lane] + hin[row + lane];
        float x1 = hhs[row + 64 + lane] + hin[row + 64 + lane];
        float s = x0 + x1, s2 = x0 * x0 + x1 * x1;
#pragma unroll
        for (int off = 32; off > 0; off >>= 1) {
            s += __shfl_xor(s, off);
            s2 += __shfl_xor(s2, off);
        }
        float mu = s * (1.f / 128.f);
        float var = s2 * (1.f / 128.f) - mu * mu;
        float rs = rsqrtf(var + 1e-5f);
        xc[r][lane]      = (x0 - mu) * rs * g1[lane] + bt1[lane];
        xc[r][lane + 64] = (x1 - mu) * rs * g1[lane + 64] + bt1[lane + 64];
    }
    __syncthreads();

    {
        int o = t;
        float acc[16];
#pragma unroll
        for (int r = 0; r < 16; ++r) acc[r] = bb1[o];
        for (int k4 = 0; k4 < 32; ++k4) {
            float wv[4];
#pragma unroll
            for (int e = 0; e < 4; ++e) wv[e] = w1[(k4 * 4 + e) * 256 + o];
#pragma unroll
            for (int r = 0; r < 16; ++r) {
                float4 xv = *(const float4*)&xc[r][k4 * 4];
                acc[r] += xv.x * wv[0] + xv.y * wv[1] + xv.z * wv[2] + xv.w * wv[3];
            }
        }
#pragma unroll
        for (int r = 0; r < 16; ++r) hid[r][o] = fmaxf(acc[r], 0.f);
    }
    __syncthreads();

    int d = t & 127;
    int g = t >> 7;
    float acc[8];
#pragma unroll
    for (int q = 0; q < 8; ++q) acc[q] = bb2[d];
    for (int k4 = 0; k4 < 64; ++k4) {
        float wv[4];
#pragma unroll
        for (int e = 0; e < 4; ++e) wv[e] = w2[(k4 * 4 + e) * 128 + d];
#pragma unroll
        for (int q = 0; q < 8; ++q) {
            float4 hv = *(const float4*)&hid[g * 8 + q][k4 * 4];
            acc[q] += hv.x * wv[0] + hv.y * wv[1] + hv.z * wv[2] + hv.w * wv[3];
        }
    }
    float resid[8];
#pragma unroll
    for (int q = 0; q < 8; ++q) resid[q] = xc[g * 8 + q][d] + acc[q];

    int halfsel = (t >> 6) & 1;
#pragma unroll
    for (int q = 0; q < 8; ++q) {
        float s = resid[q], s2 = resid[q] * resid[q];
#pragma unroll
        for (int off = 32; off > 0; off >>= 1) {
            s += __shfl_xor(s, off);
            s2 += __shfl_xor(s2, off);
        }
        if (lane == 0) red[g * 8 + q][halfsel] = make_float2(s, s2);
    }
    __syncthreads();
#pragma unroll
    for (int q = 0; q < 8; ++q) {
        int r = g * 8 + q;
        float2 ra = red[r][0], rb = red[r][1];
        float s = ra.x + rb.x, s2 = ra.y + rb.y;
        float mu = s * (1.f / 128.f);
        float var = s2 * (1.f / 128.f) - mu * mu;
        float rs = rsqrtf(var + 1e-5f);
        out[(size_t)(R0 + r) * 128 + d] = (resid[q] - mu) * rs * g2[d] + bt2[d];
    }
}

extern "C" void kernel_launch(void* const* d_in, const int* in_sizes, int n_in,
                              void* d_out, int out_size, void* d_ws, size_t ws_size,
                              hipStream_t stream) {
    const float* hin  = (const float*)d_in[0];
    const int*   adj  = (const int*)d_in[1];
    const float* W    = (const float*)d_in[2];
    const float* a    = (const float*)d_in[3];
    const float* ln1g = (const float*)d_in[4];
    const float* ln1b = (const float*)d_in[5];
    const float* w1   = (const float*)d_in[6];
    const float* b1   = (const float*)d_in[7];
    const float* w2   = (const float*)d_in[8];
    const float* b2   = (const float*)d_in[9];
    const float* ln2g = (const float*)d_in[10];
    const float* ln2b = (const float*)d_in[11];
    float* out = (float*)d_out;

    float* wh   = (float*)d_ws;                            // 4 MB
    u64*   bits = (u64*)((char*)d_ws + (4u << 20));        // 1 MB
    float* hh   = (float*)((char*)d_ws + (5u << 20));      // 4 MB

    k_pack<<<2048, 256, 0, stream>>>(adj, bits);
    k_wh<<<BB * 32, 256, (32 * 132 + 128 * 132) * sizeof(float), stream>>>(hin, W, wh);
    k_attn<<<BB * NHEAD * 16, 512, 0, stream>>>(wh, bits, a, hh);
    k_ffn<<<BB * NN / 16, 256, 0, stream>>>(hh, hin, ln1g, ln1b, w1, b1, w2, b2, ln2g, ln2b, out);
}

// Round 4
// 90.837 us; speedup vs baseline: 9.3214x; 1.4597x over previous
//
#include <hip/hip_runtime.h>

#define IN_DIM 128
#define OUT_DIM 128
#define NHEAD 8
#define HD 16
#define BB 8
#define NN 1024

typedef unsigned long long u64;
typedef float f32x4 __attribute__((ext_vector_type(4)));
typedef short bf16x8 __attribute__((ext_vector_type(8)));

// ---------------- Kernel P: pack adj_mask into 64-bit masks ----------------
__global__ __launch_bounds__(256) void k_pack(const int* __restrict__ adj,
                                              u64* __restrict__ bits) {
    int lane = threadIdx.x & 63;
    int wid = blockIdx.x * 4 + (threadIdx.x >> 6);
    for (int w = wid; w < BB * NN * 16; w += 2048 * 4) {
        int v = adj[(size_t)w * 64 + lane];
        u64 m = __ballot(v != 0);
        if (lane == 0) bits[w] = m;
    }
}

// ---------------- Kernel A: Wh[b,h,n,d] = sum_i h[b,n,i] * W[h,i,d] --------
__global__ __launch_bounds__(256) void k_wh(const float* __restrict__ hin,
                                            const float* __restrict__ W,
                                            float* __restrict__ wh) {
    extern __shared__ float smem[];
    float* h_s  = smem;             // 32 * 132
    float* wt_s = smem + 32 * 132;  // 128 * 132
    int t = threadIdx.x;
    int blk = blockIdx.x;
    int b = blk >> 5;
    int ntile = blk & 31;
    const float* hrow = hin + ((size_t)b * NN + ntile * 32) * IN_DIM;

#pragma unroll
    for (int it = 0; it < 4; ++it) {
        int g = t + 256 * it;
        int row = g >> 5, c4 = g & 31;
        float4 v = ((const float4*)hrow)[g];
        *(float4*)&h_s[row * 132 + c4 * 4] = v;
    }
    for (int g = t; g < (NHEAD * IN_DIM * HD) / 4; g += 256) {
        int hh = g >> 9;
        int rem = g & 511;
        int i = rem >> 2, d4 = rem & 3;
        float4 v = ((const float4*)W)[g];
        wt_s[(hh * 16 + d4 * 4 + 0) * 132 + i] = v.x;
        wt_s[(hh * 16 + d4 * 4 + 1) * 132 + i] = v.y;
        wt_s[(hh * 16 + d4 * 4 + 2) * 132 + i] = v.z;
        wt_s[(hh * 16 + d4 * 4 + 3) * 132 + i] = v.w;
    }
    __syncthreads();

    int hq = (t & 31) >> 2;
    int d4 = t & 3;
    int ngrp = t >> 5;
    float acc[4][4];
#pragma unroll
    for (int q = 0; q < 4; ++q)
#pragma unroll
        for (int dd = 0; dd < 4; ++dd) acc[q][dd] = 0.f;

    for (int i4 = 0; i4 < 32; ++i4) {
        float4 wr[4], hv[4];
#pragma unroll
        for (int dd = 0; dd < 4; ++dd)
            wr[dd] = *(const float4*)&wt_s[(hq * 16 + d4 * 4 + dd) * 132 + i4 * 4];
#pragma unroll
        for (int q = 0; q < 4; ++q)
            hv[q] = *(const float4*)&h_s[(ngrp * 4 + q) * 132 + i4 * 4];
#pragma unroll
        for (int q = 0; q < 4; ++q)
#pragma unroll
            for (int dd = 0; dd < 4; ++dd)
                acc[q][dd] += hv[q].x * wr[dd].x + hv[q].y * wr[dd].y +
                              hv[q].z * wr[dd].z + hv[q].w * wr[dd].w;
    }
#pragma unroll
    for (int q = 0; q < 4; ++q) {
        int row = ntile * 32 + ngrp * 4 + q;
        float4 o = make_float4(acc[q][0], acc[q][1], acc[q][2], acc[q][3]);
        *(float4*)&wh[(((size_t)b * NHEAD + hq) * NN + row) * HD + d4 * 4] = o;
    }
}

// ---------------- Kernel B: attention per (b,h), MFMA PV --------------------
// grid = B*H*8 (128-row chunks), block = 512 (8 waves, 16 rows/wave).
// P generated in-register in the 16x16x32 A-fragment layout; Wh^T staged as
// bf16 [16][1032] (pad 8 -> 2-way banks on ds_read_b128); masks as u32
// [128][33]; denominator accumulated in f32, reduced with 2 shfl_xor.
__global__ __launch_bounds__(512) void k_attn(const float* __restrict__ wh,
                                              const unsigned* __restrict__ bits32,
                                              const float* __restrict__ a,
                                              float* __restrict__ hh) {
    __shared__ __align__(16) float a_s[32];
    __shared__ unsigned mask_s[128 * 33];
    __shared__ __align__(16) float sj_s[NN];
    __shared__ float si_s[128];
    __shared__ __align__(16) unsigned short whT[16 * 1032];

    int t = threadIdx.x;
    int blk = blockIdx.x;
    int part = blk & 7;
    int bh = blk >> 3;
    int hq = bh & 7;
    int b = bh >> 3;
    int blkrow = part * 128;
    const float* whg = wh + (size_t)bh * (NN * HD);

    if (t < 32) a_s[t] = a[hq * 32 + t];

    // stage masks: 4096 u32, coalesced reads, padded rows (stride 33)
    {
        const unsigned* mb = bits32 + ((size_t)b * NN + blkrow) * 32;
#pragma unroll
        for (int it = 0; it < 8; ++it) {
            int g = t + 512 * it;
            int row = g >> 5, w = g & 31;
            mask_s[row * 33 + w] = mb[g];
        }
    }
    // stage Wh^T as bf16: thread (d = t&15, jg = t>>4) covers 32 j for its d
    {
        int d = t & 15, jg = t >> 4;
        const float* src = whg + d;
#pragma unroll
        for (int jj = 0; jj < 32; jj += 2) {
            int j = jg * 32 + jj;
            float v0 = src[(size_t)j * 16];
            float v1 = src[(size_t)(j + 1) * 16];
            unsigned u;
            asm("v_cvt_pk_bf16_f32 %0, %1, %2" : "=v"(u) : "v"(v0), "v"(v1));
            *(unsigned*)&whT[d * 1032 + j] = u;
        }
    }
    __syncthreads();

    // sj for all 1024 j (2 rows/thread), si for our 128 rows
    {
        float4 ad0 = *(const float4*)&a_s[16];
        float4 ad1 = *(const float4*)&a_s[20];
        float4 ad2 = *(const float4*)&a_s[24];
        float4 ad3 = *(const float4*)&a_s[28];
#pragma unroll
        for (int r = 0; r < 2; ++r) {
            int j = t * 2 + r;
            const float4* p = (const float4*)(whg + (size_t)j * 16);
            float4 x0 = p[0], x1 = p[1], x2 = p[2], x3 = p[3];
            sj_s[j] = x0.x * ad0.x + x0.y * ad0.y + x0.z * ad0.z + x0.w * ad0.w +
                      x1.x * ad1.x + x1.y * ad1.y + x1.z * ad1.z + x1.w * ad1.w +
                      x2.x * ad2.x + x2.y * ad2.y + x2.z * ad2.z + x2.w * ad2.w +
                      x3.x * ad3.x + x3.y * ad3.y + x3.z * ad3.z + x3.w * ad3.w;
        }
        if (t < 128) {
            float4 as0 = *(const float4*)&a_s[0];
            float4 as1 = *(const float4*)&a_s[4];
            float4 as2 = *(const float4*)&a_s[8];
            float4 as3 = *(const float4*)&a_s[12];
            int i = blkrow + t;
            const float4* p = (const float4*)(whg + (size_t)i * 16);
            float4 x0 = p[0], x1 = p[1], x2 = p[2], x3 = p[3];
            si_s[t] = x0.x * as0.x + x0.y * as0.y + x0.z * as0.z + x0.w * as0.w +
                      x1.x * as1.x + x1.y * as1.y + x1.z * as1.z + x1.w * as1.w +
                      x2.x * as2.x + x2.y * as2.y + x2.z * as2.z + x2.w * as2.w +
                      x3.x * as3.x + x3.y * as3.y + x3.z * as3.z + x3.w * as3.w;
        }
    }
    __syncthreads();

    int wv = t >> 6, lane = t & 63;
    int lo16 = lane & 15;       // A row / B col / D col
    int g = lane >> 4;          // k-slice group
    float si_r = si_s[wv * 16 + lo16];
    const unsigned* mrow = &mask_s[(wv * 16 + lo16) * 33];

    f32x4 acc = {0.f, 0.f, 0.f, 0.f};
    float lsum = 0.f;

    for (int kt = 0; kt < 32; ++kt) {
        bf16x8 bfrag = *(const bf16x8*)&whT[lo16 * 1032 + kt * 32 + g * 8];
        float4 sa = *(const float4*)&sj_s[kt * 32 + g * 8];
        float4 sb = *(const float4*)&sj_s[kt * 32 + g * 8 + 4];
        unsigned m = mrow[kt] >> (g * 8);
        float p[8];
        float sj[8] = {sa.x, sa.y, sa.z, sa.w, sb.x, sb.y, sb.z, sb.w};
#pragma unroll
        for (int e = 0; e < 8; ++e) {
            float v = si_r + sj[e];
            v = fmaxf(v, 0.f) + 0.2f * fminf(v, 0.f);
            float pe = __expf(v);
            pe = ((m >> e) & 1) ? pe : 0.f;
            lsum += pe;
            p[e] = pe;
        }
        union { bf16x8 v; unsigned u[4]; } af;
#pragma unroll
        for (int q = 0; q < 4; ++q)
            asm("v_cvt_pk_bf16_f32 %0, %1, %2" : "=v"(af.u[q]) : "v"(p[2 * q]), "v"(p[2 * q + 1]));
        acc = __builtin_amdgcn_mfma_f32_16x16x32_bf16(af.v, bfrag, acc, 0, 0, 0);
    }

    // full denominator per row: combine the 4 k-slice groups
    lsum += __shfl_xor(lsum, 16);
    lsum += __shfl_xor(lsum, 32);

    // D[row=4g+q][col=lo16] = acc[q]  (m89-verified C/D mapping)
    float* obase = hh + ((size_t)b * NN + blkrow + wv * 16) * OUT_DIM + hq * HD + lo16;
#pragma unroll
    for (int q = 0; q < 4; ++q) {
        float ls = __shfl(lsum, 4 * g + q);
        float r = (ls > 0.f) ? 1.0f / ls : 0.f;
        obase[(size_t)(4 * g + q) * OUT_DIM] = acc[q] * r;
    }
}

// ---------------- Kernel C: LN1 + FFN + LN2, 16 rows per block --------------
__global__ __launch_bounds__(256) void k_ffn(const float* __restrict__ hhs,
                                             const float* __restrict__ hin,
                                             const float* __restrict__ g1,
                                             const float* __restrict__ bt1,
                                             const float* __restrict__ w1,
                                             const float* __restrict__ bb1,
                                             const float* __restrict__ w2,
                                             const float* __restrict__ bb2,
                                             const float* __restrict__ g2,
                                             const float* __restrict__ bt2,
                                             float* __restrict__ out) {
    __shared__ float xc[16][128];
    __shared__ float hid[16][256];
    __shared__ float2 red[16][2];
    int t = threadIdx.x;
    int R0 = blockIdx.x * 16;
    int wave = t >> 6, lane = t & 63;

#pragma unroll
    for (int q = 0; q < 4; ++q) {
        int r = wave * 4 + q;
        size_t row = (size_t)(R0 + r) * 128;
        float x0 = hhs[row + lane] + hin[row + lane];
        float x1 = hhs[row + 64 + lane] + hin[row + 64 + lane];
        float s = x0 + x1, s2 = x0 * x0 + x1 * x1;
#pragma unroll
        for (int off = 32; off > 0; off >>= 1) {
            s += __shfl_xor(s, off);
            s2 += __shfl_xor(s2, off);
        }
        float mu = s * (1.f / 128.f);
        float var = s2 * (1.f / 128.f) - mu * mu;
        float rs = rsqrtf(var + 1e-5f);
        xc[r][lane]      = (x0 - mu) * rs * g1[lane] + bt1[lane];
        xc[r][lane + 64] = (x1 - mu) * rs * g1[lane + 64] + bt1[lane + 64];
    }
    __syncthreads();

    {
        int o = t;
        float acc[16];
#pragma unroll
        for (int r = 0; r < 16; ++r) acc[r] = bb1[o];
        for (int k4 = 0; k4 < 32; ++k4) {
            float wv[4];
#pragma unroll
            for (int e = 0; e < 4; ++e) wv[e] = w1[(k4 * 4 + e) * 256 + o];
#pragma unroll
            for (int r = 0; r < 16; ++r) {
                float4 xv = *(const float4*)&xc[r][k4 * 4];
                acc[r] += xv.x * wv[0] + xv.y * wv[1] + xv.z * wv[2] + xv.w * wv[3];
            }
        }
#pragma unroll
        for (int r = 0; r < 16; ++r) hid[r][o] = fmaxf(acc[r], 0.f);
    }
    __syncthreads();

    int d = t & 127;
    int g = t >> 7;
    float acc[8];
#pragma unroll
    for (int q = 0; q < 8; ++q) acc[q] = bb2[d];
    for (int k4 = 0; k4 < 64; ++k4) {
        float wv[4];
#pragma unroll
        for (int e = 0; e < 4; ++e) wv[e] = w2[(k4 * 4 + e) * 128 + d];
#pragma unroll
        for (int q = 0; q < 8; ++q) {
            float4 hv = *(const float4*)&hid[g * 8 + q][k4 * 4];
            acc[q] += hv.x * wv[0] + hv.y * wv[1] + hv.z * wv[2] + hv.w * wv[3];
        }
    }
    float resid[8];
#pragma unroll
    for (int q = 0; q < 8; ++q) resid[q] = xc[g * 8 + q][d] + acc[q];

    int halfsel = (t >> 6) & 1;
#pragma unroll
    for (int q = 0; q < 8; ++q) {
        float s = resid[q], s2 = resid[q] * resid[q];
#pragma unroll
        for (int off = 32; off > 0; off >>= 1) {
            s += __shfl_xor(s, off);
            s2 += __shfl_xor(s2, off);
        }
        if (lane == 0) red[g * 8 + q][halfsel] = make_float2(s, s2);
    }
    __syncthreads();
#pragma unroll
    for (int q = 0; q < 8; ++q) {
        int r = g * 8 + q;
        float2 ra = red[r][0], rb = red[r][1];
        float s = ra.x + rb.x, s2 = ra.y + rb.y;
        float mu = s * (1.f / 128.f);
        float var = s2 * (1.f / 128.f) - mu * mu;
        float rs = rsqrtf(var + 1e-5f);
        out[(size_t)(R0 + r) * 128 + d] = (resid[q] - mu) * rs * g2[d] + bt2[d];
    }
}

extern "C" void kernel_launch(void* const* d_in, const int* in_sizes, int n_in,
                              void* d_out, int out_size, void* d_ws, size_t ws_size,
                              hipStream_t stream) {
    const float* hin  = (const float*)d_in[0];
    const int*   adj  = (const int*)d_in[1];
    const float* W    = (const float*)d_in[2];
    const float* a    = (const float*)d_in[3];
    const float* ln1g = (const float*)d_in[4];
    const float* ln1b = (const float*)d_in[5];
    const float* w1   = (const float*)d_in[6];
    const float* b1   = (const float*)d_in[7];
    const float* w2   = (const float*)d_in[8];
    const float* b2   = (const float*)d_in[9];
    const float* ln2g = (const float*)d_in[10];
    const float* ln2b = (const float*)d_in[11];
    float* out = (float*)d_out;

    float* wh   = (float*)d_ws;                            // 4 MB
    u64*   bits = (u64*)((char*)d_ws + (4u << 20));        // 1 MB
    float* hh   = (float*)((char*)d_ws + (5u << 20));      // 4 MB

    k_pack<<<2048, 256, 0, stream>>>(adj, bits);
    k_wh<<<BB * 32, 256, (32 * 132 + 128 * 132) * sizeof(float), stream>>>(hin, W, wh);
    k_attn<<<BB * NHEAD * 8, 512, 0, stream>>>(wh, (const unsigned*)bits, a, hh);
    k_ffn<<<BB * NN / 16, 256, 0, stream>>>(hh, hin, ln1g, ln1b, w1, b1, w2, b2, ln2g, ln2b, out);
}

// Round 5
// 66.719 us; speedup vs baseline: 12.6909x; 1.3615x over previous
//
#include <hip/hip_runtime.h>
#include <hip/hip_bf16.h>

#define IN_DIM 128
#define OUT_DIM 128
#define NHEAD 8
#define HD 16
#define BB 8
#define NN 1024

typedef unsigned long long u64;
typedef float f32x4 __attribute__((ext_vector_type(4)));
typedef short bf16x8 __attribute__((ext_vector_type(8)));

// ---------------- Kernel P: pack adj_mask into 64-bit masks ----------------
__global__ __launch_bounds__(256) void k_pack(const int* __restrict__ adj,
                                              u64* __restrict__ bits) {
    int lane = threadIdx.x & 63;
    int wid = blockIdx.x * 4 + (threadIdx.x >> 6);
    for (int w = wid; w < BB * NN * 16; w += 2048 * 4) {
        int v = adj[(size_t)w * 64 + lane];
        u64 m = __ballot(v != 0);
        if (lane == 0) bits[w] = m;
    }
}

// ------------- Kernel T: transpose+cvt w1/w2 to bf16 [N][K] ----------------
// blocks 0..31: w1 [128][256] -> w1T bf16 [256][128]
// blocks 32..63: w2 [256][128] -> w2T bf16 [128][256]
__global__ __launch_bounds__(256) void k_wprep(const float* __restrict__ w1,
                                               const float* __restrict__ w2,
                                               unsigned short* __restrict__ w1T,
                                               unsigned short* __restrict__ w2T) {
    __shared__ float tile[32][33];
    int blk = blockIdx.x;
    const float* src; unsigned short* dst; int R, C;
    if (blk < 32) { src = w1; dst = w1T; R = 128; C = 256; }
    else          { src = w2; dst = w2T; R = 256; C = 128; blk -= 32; }
    int tpr = C >> 5;
    int tr = blk / tpr, tc = blk - tr * tpr;
    int r0 = tr << 5, c0 = tc << 5;
    int t = threadIdx.x, lr = t >> 5, lc = t & 31;
#pragma unroll
    for (int p = 0; p < 4; ++p)
        tile[lr + p * 8][lc] = src[(size_t)(r0 + lr + p * 8) * C + c0 + lc];
    __syncthreads();
#pragma unroll
    for (int p = 0; p < 4; ++p) {
        __hip_bfloat16 bv = __float2bfloat16(tile[lc][lr + p * 8]);
        dst[(size_t)(c0 + lr + p * 8) * R + r0 + lc] = *(unsigned short*)&bv;
    }
}

// ---------------- Kernel A: Wh[b,h,n,d] = sum_i h[b,n,i] * W[h,i,d] --------
__global__ __launch_bounds__(256) void k_wh(const float* __restrict__ hin,
                                            const float* __restrict__ W,
                                            float* __restrict__ wh) {
    extern __shared__ float smem[];
    float* h_s  = smem;             // 32 * 132
    float* wt_s = smem + 32 * 132;  // 128 * 132
    int t = threadIdx.x;
    int blk = blockIdx.x;
    int b = blk >> 5;
    int ntile = blk & 31;
    const float* hrow = hin + ((size_t)b * NN + ntile * 32) * IN_DIM;

#pragma unroll
    for (int it = 0; it < 4; ++it) {
        int g = t + 256 * it;
        int row = g >> 5, c4 = g & 31;
        float4 v = ((const float4*)hrow)[g];
        *(float4*)&h_s[row * 132 + c4 * 4] = v;
    }
    for (int g = t; g < (NHEAD * IN_DIM * HD) / 4; g += 256) {
        int hh = g >> 9;
        int rem = g & 511;
        int i = rem >> 2, d4 = rem & 3;
        float4 v = ((const float4*)W)[g];
        wt_s[(hh * 16 + d4 * 4 + 0) * 132 + i] = v.x;
        wt_s[(hh * 16 + d4 * 4 + 1) * 132 + i] = v.y;
        wt_s[(hh * 16 + d4 * 4 + 2) * 132 + i] = v.z;
        wt_s[(hh * 16 + d4 * 4 + 3) * 132 + i] = v.w;
    }
    __syncthreads();

    int hq = (t & 31) >> 2;
    int d4 = t & 3;
    int ngrp = t >> 5;
    float acc[4][4];
#pragma unroll
    for (int q = 0; q < 4; ++q)
#pragma unroll
        for (int dd = 0; dd < 4; ++dd) acc[q][dd] = 0.f;

    for (int i4 = 0; i4 < 32; ++i4) {
        float4 wr[4], hv[4];
#pragma unroll
        for (int dd = 0; dd < 4; ++dd)
            wr[dd] = *(const float4*)&wt_s[(hq * 16 + d4 * 4 + dd) * 132 + i4 * 4];
#pragma unroll
        for (int q = 0; q < 4; ++q)
            hv[q] = *(const float4*)&h_s[(ngrp * 4 + q) * 132 + i4 * 4];
#pragma unroll
        for (int q = 0; q < 4; ++q)
#pragma unroll
            for (int dd = 0; dd < 4; ++dd)
                acc[q][dd] += hv[q].x * wr[dd].x + hv[q].y * wr[dd].y +
                              hv[q].z * wr[dd].z + hv[q].w * wr[dd].w;
    }
#pragma unroll
    for (int q = 0; q < 4; ++q) {
        int row = ntile * 32 + ngrp * 4 + q;
        float4 o = make_float4(acc[q][0], acc[q][1], acc[q][2], acc[q][3]);
        *(float4*)&wh[(((size_t)b * NHEAD + hq) * NN + row) * HD + d4 * 4] = o;
    }
}

// ---------------- Kernel B: attention per (b,h), MFMA PV --------------------
__global__ __launch_bounds__(512) void k_attn(const float* __restrict__ wh,
                                              const unsigned* __restrict__ bits32,
                                              const float* __restrict__ a,
                                              float* __restrict__ hh) {
    __shared__ __align__(16) float a_s[32];
    __shared__ unsigned mask_s[128 * 33];
    __shared__ __align__(16) float sj_s[NN];
    __shared__ float si_s[128];
    __shared__ __align__(16) unsigned short whT[16 * 1032];

    int t = threadIdx.x;
    int blk = blockIdx.x;
    int part = blk & 7;
    int bh = blk >> 3;
    int hq = bh & 7;
    int b = bh >> 3;
    int blkrow = part * 128;
    const float* whg = wh + (size_t)bh * (NN * HD);

    if (t < 32) a_s[t] = a[hq * 32 + t];

    {
        const unsigned* mb = bits32 + ((size_t)b * NN + blkrow) * 32;
#pragma unroll
        for (int it = 0; it < 8; ++it) {
            int g = t + 512 * it;
            int row = g >> 5, w = g & 31;
            mask_s[row * 33 + w] = mb[g];
        }
    }
    {
        int d = t & 15, jg = t >> 4;
        const float* src = whg + d;
#pragma unroll
        for (int jj = 0; jj < 32; jj += 2) {
            int j = jg * 32 + jj;
            float v0 = src[(size_t)j * 16];
            float v1 = src[(size_t)(j + 1) * 16];
            unsigned u;
            asm("v_cvt_pk_bf16_f32 %0, %1, %2" : "=v"(u) : "v"(v0), "v"(v1));
            *(unsigned*)&whT[d * 1032 + j] = u;
        }
    }
    __syncthreads();

    {
        float4 ad0 = *(const float4*)&a_s[16];
        float4 ad1 = *(const float4*)&a_s[20];
        float4 ad2 = *(const float4*)&a_s[24];
        float4 ad3 = *(const float4*)&a_s[28];
#pragma unroll
        for (int r = 0; r < 2; ++r) {
            int j = t * 2 + r;
            const float4* p = (const float4*)(whg + (size_t)j * 16);
            float4 x0 = p[0], x1 = p[1], x2 = p[2], x3 = p[3];
            sj_s[j] = x0.x * ad0.x + x0.y * ad0.y + x0.z * ad0.z + x0.w * ad0.w +
                      x1.x * ad1.x + x1.y * ad1.y + x1.z * ad1.z + x1.w * ad1.w +
                      x2.x * ad2.x + x2.y * ad2.y + x2.z * ad2.z + x2.w * ad2.w +
                      x3.x * ad3.x + x3.y * ad3.y + x3.z * ad3.z + x3.w * ad3.w;
        }
        if (t < 128) {
            float4 as0 = *(const float4*)&a_s[0];
            float4 as1 = *(const float4*)&a_s[4];
            float4 as2 = *(const float4*)&a_s[8];
            float4 as3 = *(const float4*)&a_s[12];
            int i = blkrow + t;
            const float4* p = (const float4*)(whg + (size_t)i * 16);
            float4 x0 = p[0], x1 = p[1], x2 = p[2], x3 = p[3];
            si_s[t] = x0.x * as0.x + x0.y * as0.y + x0.z * as0.z + x0.w * as0.w +
                      x1.x * as1.x + x1.y * as1.y + x1.z * as1.z + x1.w * as1.w +
                      x2.x * as2.x + x2.y * as2.y + x2.z * as2.z + x2.w * as2.w +
                      x3.x * as3.x + x3.y * as3.y + x3.z * as3.z + x3.w * as3.w;
        }
    }
    __syncthreads();

    int wv = t >> 6, lane = t & 63;
    int lo16 = lane & 15;
    int g = lane >> 4;
    float si_r = si_s[wv * 16 + lo16];
    const unsigned* mrow = &mask_s[(wv * 16 + lo16) * 33];

    f32x4 acc = {0.f, 0.f, 0.f, 0.f};
    float lsum = 0.f;

    for (int kt = 0; kt < 32; ++kt) {
        bf16x8 bfrag = *(const bf16x8*)&whT[lo16 * 1032 + kt * 32 + g * 8];
        float4 sa = *(const float4*)&sj_s[kt * 32 + g * 8];
        float4 sb = *(const float4*)&sj_s[kt * 32 + g * 8 + 4];
        unsigned m = mrow[kt] >> (g * 8);
        float p[8];
        float sj[8] = {sa.x, sa.y, sa.z, sa.w, sb.x, sb.y, sb.z, sb.w};
#pragma unroll
        for (int e = 0; e < 8; ++e) {
            float v = si_r + sj[e];
            v = fmaxf(v, 0.f) + 0.2f * fminf(v, 0.f);
            float pe = __expf(v);
            pe = ((m >> e) & 1) ? pe : 0.f;
            lsum += pe;
            p[e] = pe;
        }
        union { bf16x8 v; unsigned u[4]; } af;
#pragma unroll
        for (int q = 0; q < 4; ++q)
            asm("v_cvt_pk_bf16_f32 %0, %1, %2" : "=v"(af.u[q]) : "v"(p[2 * q]), "v"(p[2 * q + 1]));
        acc = __builtin_amdgcn_mfma_f32_16x16x32_bf16(af.v, bfrag, acc, 0, 0, 0);
    }

    lsum += __shfl_xor(lsum, 16);
    lsum += __shfl_xor(lsum, 32);

    float* obase = hh + ((size_t)b * NN + blkrow + wv * 16) * OUT_DIM + hq * HD + lo16;
#pragma unroll
    for (int q = 0; q < 4; ++q) {
        float ls = __shfl(lsum, 4 * g + q);
        float r = (ls > 0.f) ? 1.0f / ls : 0.f;
        obase[(size_t)(4 * g + q) * OUT_DIM] = acc[q] * r;
    }
}

// -------- Kernel C: LN1 + FFN (MFMA bf16) + LN2, 32 rows per block ----------
// 512 thr = 8 waves. B-fragments of both GEMMs in registers (loaded at top,
// latency hidden under LN1). xc/hid staged bf16 in LDS with XOR swizzle
// (byte ^= (m&7)<<4) so A-frag ds_read_b128 is ~2-way (free) not 32-way.
__global__ __launch_bounds__(512, 1) void k_ffn(const float* __restrict__ hhs,
                                                const float* __restrict__ hin,
                                                const float* __restrict__ g1,
                                                const float* __restrict__ bt1,
                                                const unsigned short* __restrict__ w1T,
                                                const float* __restrict__ bb1,
                                                const unsigned short* __restrict__ w2T,
                                                const float* __restrict__ bb2,
                                                const float* __restrict__ g2,
                                                const float* __restrict__ bt2,
                                                float* __restrict__ out) {
    __shared__ float xc_f[32][128];                       // LN1 out (residual)
    __shared__ float y_f[32][132];                        // GEMM2 out
    __shared__ __align__(16) unsigned short xc_bf[32 * 128];   // swizzled
    __shared__ __align__(16) unsigned short hid_bf[32 * 256];  // swizzled

    int t = threadIdx.x;
    int R0 = blockIdx.x * 32;
    int wv = t >> 6, lane = t & 63;
    int lo = lane & 15, g = lane >> 4;

    // ---- issue all B-fragment + bias loads first (hide L2 latency) ----
    bf16x8 b1f[2][4];
#pragma unroll
    for (int jt = 0; jt < 2; ++jt) {
        int n = (wv * 2 + jt) * 16 + lo;
#pragma unroll
        for (int kt = 0; kt < 4; ++kt)
            b1f[jt][kt] = *(const bf16x8*)&w1T[(size_t)n * 128 + kt * 32 + g * 8];
    }
    bf16x8 b2f[8];
    {
        int n = wv * 16 + lo;
#pragma unroll
        for (int kt = 0; kt < 8; ++kt)
            b2f[kt] = *(const bf16x8*)&w2T[(size_t)n * 256 + kt * 32 + g * 8];
    }
    float b1v[2];
    b1v[0] = bb1[(wv * 2 + 0) * 16 + lo];
    b1v[1] = bb1[(wv * 2 + 1) * 16 + lo];
    float b2v = bb2[wv * 16 + lo];

    // ---- LN1: residual + layernorm; thread (r = t>>4, c = t&15) owns 8 cols
    {
        int r = t >> 4, c = t & 15;
        size_t row = (size_t)(R0 + r) * 128;
        float4 ha = *(const float4*)&hhs[row + c * 8];
        float4 hb = *(const float4*)&hhs[row + c * 8 + 4];
        float4 ia = *(const float4*)&hin[row + c * 8];
        float4 ib = *(const float4*)&hin[row + c * 8 + 4];
        float x[8] = {ha.x + ia.x, ha.y + ia.y, ha.z + ia.z, ha.w + ia.w,
                      hb.x + ib.x, hb.y + ib.y, hb.z + ib.z, hb.w + ib.w};
        float s = 0.f, s2 = 0.f;
#pragma unroll
        for (int j = 0; j < 8; ++j) { s += x[j]; s2 += x[j] * x[j]; }
#pragma unroll
        for (int off = 8; off > 0; off >>= 1) {
            s += __shfl_xor(s, off);
            s2 += __shfl_xor(s2, off);
        }
        float mu = s * (1.f / 128.f);
        float var = s2 * (1.f / 128.f) - mu * mu;
        float rs = rsqrtf(var + 1e-5f);
        float4 ga = *(const float4*)&g1[c * 8], gb = *(const float4*)&g1[c * 8 + 4];
        float4 ba = *(const float4*)&bt1[c * 8], bb = *(const float4*)&bt1[c * 8 + 4];
        float gg[8] = {ga.x, ga.y, ga.z, ga.w, gb.x, gb.y, gb.z, gb.w};
        float bbv[8] = {ba.x, ba.y, ba.z, ba.w, bb.x, bb.y, bb.z, bb.w};
        float xo[8];
#pragma unroll
        for (int j = 0; j < 8; ++j) xo[j] = (x[j] - mu) * rs * gg[j] + bbv[j];
        *(float4*)&xc_f[r][c * 8]     = make_float4(xo[0], xo[1], xo[2], xo[3]);
        *(float4*)&xc_f[r][c * 8 + 4] = make_float4(xo[4], xo[5], xo[6], xo[7]);
        union { uint4 v; unsigned u[4]; } pk;
#pragma unroll
        for (int q = 0; q < 4; ++q)
            asm("v_cvt_pk_bf16_f32 %0, %1, %2" : "=v"(pk.u[q]) : "v"(xo[2 * q]), "v"(xo[2 * q + 1]));
        int byte = (r * 256 + c * 16) ^ ((r & 7) << 4);
        *(uint4*)((char*)xc_bf + byte) = pk.v;
    }
    __syncthreads();

    // ---- GEMM1: hid = relu(xc @ w1 + b1), wave covers cols [wv*32, wv*32+32)
    {
        bf16x8 af[2][4];
#pragma unroll
        for (int mt = 0; mt < 2; ++mt) {
            int m = mt * 16 + lo;
#pragma unroll
            for (int kt = 0; kt < 4; ++kt) {
                int byte = (m * 256 + kt * 64 + g * 16) ^ ((m & 7) << 4);
                af[mt][kt] = *(const bf16x8*)((const char*)xc_bf + byte);
            }
        }
#pragma unroll
        for (int mt = 0; mt < 2; ++mt)
#pragma unroll
            for (int jt = 0; jt < 2; ++jt) {
                f32x4 acc = {0.f, 0.f, 0.f, 0.f};
#pragma unroll
                for (int kt = 0; kt < 4; ++kt)
                    acc = __builtin_amdgcn_mfma_f32_16x16x32_bf16(af[mt][kt], b1f[jt][kt], acc, 0, 0, 0);
                int n = (wv * 2 + jt) * 16 + lo;
#pragma unroll
                for (int q = 0; q < 4; ++q) {
                    float hv = fmaxf(acc[q] + b1v[jt], 0.f);
                    int m = mt * 16 + 4 * g + q;
                    int byte = (m * 512 + n * 2) ^ ((m & 7) << 4);
                    __hip_bfloat16 bv = __float2bfloat16(hv);
                    *(unsigned short*)((char*)hid_bf + byte) = *(unsigned short*)&bv;
                }
            }
    }
    __syncthreads();

    // ---- GEMM2: y = hid @ w2 + b2, wave covers out cols [wv*16, wv*16+16)
    {
        f32x4 acc2[2] = {{0.f, 0.f, 0.f, 0.f}, {0.f, 0.f, 0.f, 0.f}};
#pragma unroll
        for (int mt = 0; mt < 2; ++mt) {
            int m = mt * 16 + lo;
#pragma unroll
            for (int kt = 0; kt < 8; ++kt) {
                int byte = (m * 512 + kt * 64 + g * 16) ^ ((m & 7) << 4);
                bf16x8 a = *(const bf16x8*)((const char*)hid_bf + byte);
                acc2[mt] = __builtin_amdgcn_mfma_f32_16x16x32_bf16(a, b2f[kt], acc2[mt], 0, 0, 0);
            }
        }
        int n = wv * 16 + lo;
#pragma unroll
        for (int mt = 0; mt < 2; ++mt)
#pragma unroll
            for (int q = 0; q < 4; ++q)
                y_f[mt * 16 + 4 * g + q][n] = acc2[mt][q] + b2v;
    }
    __syncthreads();

    // ---- LN2: resid = xc + y, layernorm, store
    {
        int r = t >> 4, c = t & 15;
        float xv[8];
        float s = 0.f, s2 = 0.f;
#pragma unroll
        for (int j = 0; j < 8; ++j) {
            float v = xc_f[r][c * 8 + j] + y_f[r][c * 8 + j];
            xv[j] = v; s += v; s2 += v * v;
        }
#pragma unroll
        for (int off = 8; off > 0; off >>= 1) {
            s += __shfl_xor(s, off);
            s2 += __shfl_xor(s2, off);
        }
        float mu = s * (1.f / 128.f);
        float var = s2 * (1.f / 128.f) - mu * mu;
        float rs = rsqrtf(var + 1e-5f);
        float4 ga = *(const float4*)&g2[c * 8], gb = *(const float4*)&g2[c * 8 + 4];
        float4 ba = *(const float4*)&bt2[c * 8], bb = *(const float4*)&bt2[c * 8 + 4];
        float o[8] = {(xv[0] - mu) * rs * ga.x + ba.x, (xv[1] - mu) * rs * ga.y + ba.y,
                      (xv[2] - mu) * rs * ga.z + ba.z, (xv[3] - mu) * rs * ga.w + ba.w,
                      (xv[4] - mu) * rs * gb.x + bb.x, (xv[5] - mu) * rs * gb.y + bb.y,
                      (xv[6] - mu) * rs * gb.z + bb.z, (xv[7] - mu) * rs * gb.w + bb.w};
        size_t row = (size_t)(R0 + r) * 128;
        *(float4*)&out[row + c * 8]     = make_float4(o[0], o[1], o[2], o[3]);
        *(float4*)&out[row + c * 8 + 4] = make_float4(o[4], o[5], o[6], o[7]);
    }
}

extern "C" void kernel_launch(void* const* d_in, const int* in_sizes, int n_in,
                              void* d_out, int out_size, void* d_ws, size_t ws_size,
                              hipStream_t stream) {
    const float* hin  = (const float*)d_in[0];
    const int*   adj  = (const int*)d_in[1];
    const float* W    = (const float*)d_in[2];
    const float* a    = (const float*)d_in[3];
    const float* ln1g = (const float*)d_in[4];
    const float* ln1b = (const float*)d_in[5];
    const float* w1   = (const float*)d_in[6];
    const float* b1   = (const float*)d_in[7];
    const float* w2   = (const float*)d_in[8];
    const float* b2   = (const float*)d_in[9];
    const float* ln2g = (const float*)d_in[10];
    const float* ln2b = (const float*)d_in[11];
    float* out = (float*)d_out;

    float* wh             = (float*)d_ws;                          // 4 MB
    u64*   bits           = (u64*)((char*)d_ws + (4u << 20));      // 1 MB
    float* hh             = (float*)((char*)d_ws + (5u << 20));    // 4 MB
    unsigned short* w1T   = (unsigned short*)((char*)d_ws + (9u << 20));          // 64 KB
    unsigned short* w2T   = (unsigned short*)((char*)d_ws + (9u << 20) + 65536);  // 64 KB

    k_pack<<<2048, 256, 0, stream>>>(adj, bits);
    k_wprep<<<64, 256, 0, stream>>>(w1, w2, w1T, w2T);
    k_wh<<<BB * 32, 256, (32 * 132 + 128 * 132) * sizeof(float), stream>>>(hin, W, wh);
    k_attn<<<BB * NHEAD * 8, 512, 0, stream>>>(wh, (const unsigned*)bits, a, hh);
    k_ffn<<<BB * NN / 32, 512, 0, stream>>>(hh, hin, ln1g, ln1b, w1T, b1, w2T, b2, ln2g, ln2b, out);
}

// Round 6
// 62.902 us; speedup vs baseline: 13.4611x; 1.0607x over previous
//
#include <hip/hip_runtime.h>
#include <hip/hip_bf16.h>

#define IN_DIM 128
#define OUT_DIM 128
#define NHEAD 8
#define HD 16
#define BB 8
#define NN 1024
#define LOG2E 1.44269504f

typedef unsigned long long u64;
typedef float f32x4 __attribute__((ext_vector_type(4)));
typedef short bf16x8 __attribute__((ext_vector_type(8)));

// ---- Kernel PREP (fused): blocks [0,256) Wh->whT/si/sj ; [256,2304) pack ;
//      [2304,2368) w1/w2 transpose+cvt.
__global__ __launch_bounds__(256) void k_prep(
    const float* __restrict__ hin, const float* __restrict__ W,
    const float* __restrict__ a, const int* __restrict__ adj,
    u64* __restrict__ bits, unsigned short* __restrict__ whT,
    float* __restrict__ si_g, float* __restrict__ sj_g,
    const float* __restrict__ w1, const float* __restrict__ w2,
    unsigned short* __restrict__ w1T, unsigned short* __restrict__ w2T)
{
    __shared__ float smem[32 * 132];
    int blk = blockIdx.x;
    int t = threadIdx.x;

    if (blk < 256) {
        // ---- Wh part: 32 rows per block; W read straight from L1/L2 ----
        int b = blk >> 5, ntile = blk & 31;
        const float* hrow = hin + ((size_t)b * NN + ntile * 32) * IN_DIM;
#pragma unroll
        for (int it = 0; it < 4; ++it) {
            int g = t + 256 * it;
            int row = g >> 5, c4 = g & 31;
            float4 v = ((const float4*)hrow)[g];
            *(float4*)&smem[row * 132 + c4 * 4] = v;
        }
        __syncthreads();

        int d4 = t & 3;             // lane bits 0-1
        int hq = (t >> 2) & 7;      // lane bits 2-4
        int ngrp = t >> 5;          // 4 rows per thread
        float acc[4][4];
#pragma unroll
        for (int q = 0; q < 4; ++q)
#pragma unroll
            for (int dd = 0; dd < 4; ++dd) acc[q][dd] = 0.f;

        for (int i4 = 0; i4 < 32; ++i4) {
            float4 wf[4];
#pragma unroll
            for (int k = 0; k < 4; ++k)
                wf[k] = *(const float4*)&W[((size_t)hq * 128 + i4 * 4 + k) * 16 + d4 * 4];
            float4 hv[4];
#pragma unroll
            for (int q = 0; q < 4; ++q)
                hv[q] = *(const float4*)&smem[(ngrp * 4 + q) * 132 + i4 * 4];
#pragma unroll
            for (int q = 0; q < 4; ++q) {
                acc[q][0] += hv[q].x * wf[0].x + hv[q].y * wf[1].x + hv[q].z * wf[2].x + hv[q].w * wf[3].x;
                acc[q][1] += hv[q].x * wf[0].y + hv[q].y * wf[1].y + hv[q].z * wf[2].y + hv[q].w * wf[3].y;
                acc[q][2] += hv[q].x * wf[0].z + hv[q].y * wf[1].z + hv[q].z * wf[2].z + hv[q].w * wf[3].z;
                acc[q][3] += hv[q].x * wf[0].w + hv[q].y * wf[1].w + hv[q].z * wf[2].w + hv[q].w * wf[3].w;
            }
        }

        int bh = b * NHEAD + hq;
        int rowbase = ntile * 32 + ngrp * 4;

        // si/sj (f32, prescaled by log2e); reduce over d4 = lane bits 0-1
        float asrc[4], adst[4];
#pragma unroll
        for (int dd = 0; dd < 4; ++dd) {
            asrc[dd] = a[hq * 32 + d4 * 4 + dd];
            adst[dd] = a[hq * 32 + 16 + d4 * 4 + dd];
        }
#pragma unroll
        for (int q = 0; q < 4; ++q) {
            float psi = acc[q][0] * asrc[0] + acc[q][1] * asrc[1] + acc[q][2] * asrc[2] + acc[q][3] * asrc[3];
            float psj = acc[q][0] * adst[0] + acc[q][1] * adst[1] + acc[q][2] * adst[2] + acc[q][3] * adst[3];
            psi += __shfl_xor(psi, 1); psi += __shfl_xor(psi, 2);
            psj += __shfl_xor(psj, 1); psj += __shfl_xor(psj, 2);
            if (d4 == 0) {
                si_g[(size_t)bh * NN + rowbase + q] = psi * LOG2E;
                sj_g[(size_t)bh * NN + rowbase + q] = psj * LOG2E;
            }
        }

        // whT bf16 [bh][d][row]: pack 4 consecutive rows -> dwordx2 store
#pragma unroll
        for (int dd = 0; dd < 4; ++dd) {
            unsigned u0, u1;
            asm("v_cvt_pk_bf16_f32 %0, %1, %2" : "=v"(u0) : "v"(acc[0][dd]), "v"(acc[1][dd]));
            asm("v_cvt_pk_bf16_f32 %0, %1, %2" : "=v"(u1) : "v"(acc[2][dd]), "v"(acc[3][dd]));
            uint2 pk = make_uint2(u0, u1);
            *(uint2*)&whT[((size_t)bh * 16 + d4 * 4 + dd) * 1024 + rowbase] = pk;
        }
    } else if (blk < 2304) {
        // ---- pack adj into 64-bit masks ----
        int lane = t & 63;
        int wid = (blk - 256) * 4 + (t >> 6);
        for (int w = wid; w < BB * NN * 16; w += 2048 * 4) {
            int v = adj[(size_t)w * 64 + lane];
            u64 m = __ballot(v != 0);
            if (lane == 0) bits[w] = m;
        }
    } else {
        // ---- w1/w2 transpose + cvt bf16 ----
        int bb = blk - 2304;
        const float* src; unsigned short* dst; int R, C;
        if (bb < 32) { src = w1; dst = w1T; R = 128; C = 256; }
        else         { src = w2; dst = w2T; R = 256; C = 128; bb -= 32; }
        int tpr = C >> 5;
        int tr = bb / tpr, tc = bb - tr * tpr;
        int r0 = tr << 5, c0 = tc << 5;
        int lr = t >> 5, lc = t & 31;
#pragma unroll
        for (int p = 0; p < 4; ++p)
            smem[(lr + p * 8) * 33 + lc] = src[(size_t)(r0 + lr + p * 8) * C + c0 + lc];
        __syncthreads();
#pragma unroll
        for (int p = 0; p < 4; ++p) {
            __hip_bfloat16 bv = __float2bfloat16(smem[lc * 33 + lr + p * 8]);
            dst[(size_t)(c0 + lr + p * 8) * R + r0 + lc] = *(unsigned short*)&bv;
        }
    }
}

// ---- Kernel B: attention per (b,h), MFMA PV, lean staging ----
// grid = B*H*8 (128-row parts), 512 thr. LDS = whT 33KB (chunk-XOR-swizzled)
// + sj 4KB. Masks gathered from L2 with distance-1 prefetch. Logits
// prescaled by log2e -> v_exp_f32 (2^x) directly; leaky = 0.6x + 0.4|x|.
__global__ __launch_bounds__(512, 3) void k_attn(
    const unsigned short* __restrict__ whT,
    const unsigned* __restrict__ bits32,
    const float* __restrict__ si_g, const float* __restrict__ sj_g,
    float* __restrict__ hh)
{
    __shared__ __align__(16) unsigned short whT_s[16 * 1032];
    __shared__ __align__(16) float sj_s[NN];
    int t = threadIdx.x;
    int blk = blockIdx.x;
    int part = blk & 7;
    int bh = blk >> 3;
    int hq = bh & 7, b = bh >> 3;
    int blkrow = part * 128;

    {
        const uint4* src = (const uint4*)(whT + (size_t)bh * 16 * 1024);
#pragma unroll
        for (int it = 0; it < 4; ++it) {
            int g = t + 512 * it;            // uint4 index (2048 total)
            int d = g >> 7, c8 = g & 127;    // 128 chunks of 8 bf16 per row
            uint4 v = src[g];
            *(uint4*)&whT_s[d * 1032 + ((c8 ^ (d & 3)) * 8)] = v;
        }
        if (t < 256) *(float4*)&sj_s[t * 4] = ((const float4*)(sj_g + (size_t)bh * NN))[t];
    }
    __syncthreads();

    int wv = t >> 6, lane = t & 63;
    int lo16 = lane & 15, g = lane >> 4;
    int row = blkrow + wv * 16 + lo16;
    float si_r = si_g[(size_t)bh * NN + row];
    const unsigned* mrow = bits32 + ((size_t)b * NN + row) * 32;

    f32x4 acc = {0.f, 0.f, 0.f, 0.f};
    float lsum = 0.f;
    unsigned m = mrow[0];
#pragma unroll 4
    for (int kt = 0; kt < 32; ++kt) {
        unsigned m_next = (kt < 31) ? mrow[kt + 1] : 0u;
        bf16x8 bfrag = *(const bf16x8*)&whT_s[lo16 * 1032 + (((kt * 4 + g) ^ (lo16 & 3)) * 8)];
        float4 sa = *(const float4*)&sj_s[kt * 32 + g * 8];
        float4 sb = *(const float4*)&sj_s[kt * 32 + g * 8 + 4];
        unsigned mm = m >> (g * 8);
        float sj[8] = {sa.x, sa.y, sa.z, sa.w, sb.x, sb.y, sb.z, sb.w};
        float p[8];
#pragma unroll
        for (int e = 0; e < 8; ++e) {
            float v = si_r + sj[e];
            float lv = __builtin_fmaf(0.4f, __builtin_fabsf(v), 0.6f * v);
            lv = ((mm >> e) & 1) ? lv : -150.f;
            float pe;
            asm("v_exp_f32 %0, %1" : "=v"(pe) : "v"(lv));
            lsum += pe;
            p[e] = pe;
        }
        union { bf16x8 v; unsigned u[4]; } af;
#pragma unroll
        for (int q = 0; q < 4; ++q)
            asm("v_cvt_pk_bf16_f32 %0, %1, %2" : "=v"(af.u[q]) : "v"(p[2 * q]), "v"(p[2 * q + 1]));
        acc = __builtin_amdgcn_mfma_f32_16x16x32_bf16(af.v, bfrag, acc, 0, 0, 0);
        m = m_next;
    }

    lsum += __shfl_xor(lsum, 16);
    lsum += __shfl_xor(lsum, 32);

    float* obase = hh + ((size_t)b * NN + blkrow + wv * 16) * OUT_DIM + hq * HD + lo16;
#pragma unroll
    for (int q = 0; q < 4; ++q) {
        float ls = __shfl(lsum, 4 * g + q);
        float r = (ls > 0.f) ? 1.0f / ls : 0.f;
        obase[(size_t)(4 * g + q) * OUT_DIM] = acc[q] * r;
    }
}

// -------- Kernel C: LN1 + FFN (MFMA bf16) + LN2, 32 rows per block ----------
__global__ __launch_bounds__(512, 1) void k_ffn(const float* __restrict__ hhs,
                                                const float* __restrict__ hin,
                                                const float* __restrict__ g1,
                                                const float* __restrict__ bt1,
                                                const unsigned short* __restrict__ w1T,
                                                const float* __restrict__ bb1,
                                                const unsigned short* __restrict__ w2T,
                                                const float* __restrict__ bb2,
                                                const float* __restrict__ g2,
                                                const float* __restrict__ bt2,
                                                float* __restrict__ out) {
    __shared__ float xc_f[32][128];
    __shared__ float y_f[32][132];
    __shared__ __align__(16) unsigned short xc_bf[32 * 128];
    __shared__ __align__(16) unsigned short hid_bf[32 * 256];

    int t = threadIdx.x;
    int R0 = blockIdx.x * 32;
    int wv = t >> 6, lane = t & 63;
    int lo = lane & 15, g = lane >> 4;

    bf16x8 b1f[2][4];
#pragma unroll
    for (int jt = 0; jt < 2; ++jt) {
        int n = (wv * 2 + jt) * 16 + lo;
#pragma unroll
        for (int kt = 0; kt < 4; ++kt)
            b1f[jt][kt] = *(const bf16x8*)&w1T[(size_t)n * 128 + kt * 32 + g * 8];
    }
    bf16x8 b2f[8];
    {
        int n = wv * 16 + lo;
#pragma unroll
        for (int kt = 0; kt < 8; ++kt)
            b2f[kt] = *(const bf16x8*)&w2T[(size_t)n * 256 + kt * 32 + g * 8];
    }
    float b1v[2];
    b1v[0] = bb1[(wv * 2 + 0) * 16 + lo];
    b1v[1] = bb1[(wv * 2 + 1) * 16 + lo];
    float b2v = bb2[wv * 16 + lo];

    {
        int r = t >> 4, c = t & 15;
        size_t row = (size_t)(R0 + r) * 128;
        float4 ha = *(const float4*)&hhs[row + c * 8];
        float4 hb = *(const float4*)&hhs[row + c * 8 + 4];
        float4 ia = *(const float4*)&hin[row + c * 8];
        float4 ib = *(const float4*)&hin[row + c * 8 + 4];
        float x[8] = {ha.x + ia.x, ha.y + ia.y, ha.z + ia.z, ha.w + ia.w,
                      hb.x + ib.x, hb.y + ib.y, hb.z + ib.z, hb.w + ib.w};
        float s = 0.f, s2 = 0.f;
#pragma unroll
        for (int j = 0; j < 8; ++j) { s += x[j]; s2 += x[j] * x[j]; }
#pragma unroll
        for (int off = 8; off > 0; off >>= 1) {
            s += __shfl_xor(s, off);
            s2 += __shfl_xor(s2, off);
        }
        float mu = s * (1.f / 128.f);
        float var = s2 * (1.f / 128.f) - mu * mu;
        float rs = rsqrtf(var + 1e-5f);
        float4 ga = *(const float4*)&g1[c * 8], gb = *(const float4*)&g1[c * 8 + 4];
        float4 ba = *(const float4*)&bt1[c * 8], bb = *(const float4*)&bt1[c * 8 + 4];
        float gg[8] = {ga.x, ga.y, ga.z, ga.w, gb.x, gb.y, gb.z, gb.w};
        float bbv[8] = {ba.x, ba.y, ba.z, ba.w, bb.x, bb.y, bb.z, bb.w};
        float xo[8];
#pragma unroll
        for (int j = 0; j < 8; ++j) xo[j] = (x[j] - mu) * rs * gg[j] + bbv[j];
        *(float4*)&xc_f[r][c * 8]     = make_float4(xo[0], xo[1], xo[2], xo[3]);
        *(float4*)&xc_f[r][c * 8 + 4] = make_float4(xo[4], xo[5], xo[6], xo[7]);
        union { uint4 v; unsigned u[4]; } pk;
#pragma unroll
        for (int q = 0; q < 4; ++q)
            asm("v_cvt_pk_bf16_f32 %0, %1, %2" : "=v"(pk.u[q]) : "v"(xo[2 * q]), "v"(xo[2 * q + 1]));
        int byte = (r * 256 + c * 16) ^ ((r & 7) << 4);
        *(uint4*)((char*)xc_bf + byte) = pk.v;
    }
    __syncthreads();

    {
        bf16x8 af[2][4];
#pragma unroll
        for (int mt = 0; mt < 2; ++mt) {
            int m = mt * 16 + lo;
#pragma unroll
            for (int kt = 0; kt < 4; ++kt) {
                int byte = (m * 256 + kt * 64 + g * 16) ^ ((m & 7) << 4);
                af[mt][kt] = *(const bf16x8*)((const char*)xc_bf + byte);
            }
        }
#pragma unroll
        for (int mt = 0; mt < 2; ++mt)
#pragma unroll
            for (int jt = 0; jt < 2; ++jt) {
                f32x4 acc = {0.f, 0.f, 0.f, 0.f};
#pragma unroll
                for (int kt = 0; kt < 4; ++kt)
                    acc = __builtin_amdgcn_mfma_f32_16x16x32_bf16(af[mt][kt], b1f[jt][kt], acc, 0, 0, 0);
                int n = (wv * 2 + jt) * 16 + lo;
#pragma unroll
                for (int q = 0; q < 4; ++q) {
                    float hv = fmaxf(acc[q] + b1v[jt], 0.f);
                    int m = mt * 16 + 4 * g + q;
                    int byte = (m * 512 + n * 2) ^ ((m & 7) << 4);
                    __hip_bfloat16 bv = __float2bfloat16(hv);
                    *(unsigned short*)((char*)hid_bf + byte) = *(unsigned short*)&bv;
                }
            }
    }
    __syncthreads();

    {
        f32x4 acc2[2] = {{0.f, 0.f, 0.f, 0.f}, {0.f, 0.f, 0.f, 0.f}};
#pragma unroll
        for (int mt = 0; mt < 2; ++mt) {
            int m = mt * 16 + lo;
#pragma unroll
            for (int kt = 0; kt < 8; ++kt) {
                int byte = (m * 512 + kt * 64 + g * 16) ^ ((m & 7) << 4);
                bf16x8 a = *(const bf16x8*)((const char*)hid_bf + byte);
                acc2[mt] = __builtin_amdgcn_mfma_f32_16x16x32_bf16(a, b2f[kt], acc2[mt], 0, 0, 0);
            }
        }
        int n = wv * 16 + lo;
#pragma unroll
        for (int mt = 0; mt < 2; ++mt)
#pragma unroll
            for (int q = 0; q < 4; ++q)
                y_f[mt * 16 + 4 * g + q][n] = acc2[mt][q] + b2v;
    }
    __syncthreads();

    {
        int r = t >> 4, c = t & 15;
        float xv[8];
        float s = 0.f, s2 = 0.f;
#pragma unroll
        for (int j = 0; j < 8; ++j) {
            float v = xc_f[r][c * 8 + j] + y_f[r][c * 8 + j];
            xv[j] = v; s += v; s2 += v * v;
        }
#pragma unroll
        for (int off = 8; off > 0; off >>= 1) {
            s += __shfl_xor(s, off);
            s2 += __shfl_xor(s2, off);
        }
        float mu = s * (1.f / 128.f);
        float var = s2 * (1.f / 128.f) - mu * mu;
        float rs = rsqrtf(var + 1e-5f);
        float4 ga = *(const float4*)&g2[c * 8], gb = *(const float4*)&g2[c * 8 + 4];
        float4 ba = *(const float4*)&bt2[c * 8], bb = *(const float4*)&bt2[c * 8 + 4];
        float o[8] = {(xv[0] - mu) * rs * ga.x + ba.x, (xv[1] - mu) * rs * ga.y + ba.y,
                      (xv[2] - mu) * rs * ga.z + ba.z, (xv[3] - mu) * rs * ga.w + ba.w,
                      (xv[4] - mu) * rs * gb.x + bb.x, (xv[5] - mu) * rs * gb.y + bb.y,
                      (xv[6] - mu) * rs * gb.z + bb.z, (xv[7] - mu) * rs * gb.w + bb.w};
        size_t row = (size_t)(R0 + r) * 128;
        *(float4*)&out[row + c * 8]     = make_float4(o[0], o[1], o[2], o[3]);
        *(float4*)&out[row + c * 8 + 4] = make_float4(o[4], o[5], o[6], o[7]);
    }
}

extern "C" void kernel_launch(void* const* d_in, const int* in_sizes, int n_in,
                              void* d_out, int out_size, void* d_ws, size_t ws_size,
                              hipStream_t stream) {
    const float* hin  = (const float*)d_in[0];
    const int*   adj  = (const int*)d_in[1];
    const float* W    = (const float*)d_in[2];
    const float* a    = (const float*)d_in[3];
    const float* ln1g = (const float*)d_in[4];
    const float* ln1b = (const float*)d_in[5];
    const float* w1   = (const float*)d_in[6];
    const float* b1   = (const float*)d_in[7];
    const float* w2   = (const float*)d_in[8];
    const float* b2   = (const float*)d_in[9];
    const float* ln2g = (const float*)d_in[10];
    const float* ln2b = (const float*)d_in[11];
    float* out = (float*)d_out;

    u64* bits           = (u64*)d_ws;                                              // 1 MB
    unsigned short* whT = (unsigned short*)((char*)d_ws + (1u << 20));             // 2 MB
    float* si_g         = (float*)((char*)d_ws + (3u << 20));                      // 256 KB
    float* sj_g         = (float*)((char*)d_ws + (3u << 20) + (256u << 10));       // 256 KB
    float* hh           = (float*)((char*)d_ws + (3u << 20) + (512u << 10));       // 4 MB
    unsigned short* w1T = (unsigned short*)((char*)d_ws + (7u << 20) + (512u << 10));        // 64 KB
    unsigned short* w2T = (unsigned short*)((char*)d_ws + (7u << 20) + (512u << 10) + 65536);// 64 KB

    k_prep<<<2368, 256, 0, stream>>>(hin, W, a, adj, bits, whT, si_g, sj_g,
                                     w1, w2, w1T, w2T);
    k_attn<<<BB * NHEAD * 8, 512, 0, stream>>>(whT, (const unsigned*)bits, si_g, sj_g, hh);
    k_ffn<<<BB * NN / 32, 512, 0, stream>>>(hh, hin, ln1g, ln1b, w1T, b1, w2T, b2, ln2g, ln2b, out);
}